// Round 6
// baseline (460.556 us; speedup 1.0000x reference)
//
#include <hip/hip_runtime.h>

typedef __attribute__((ext_vector_type(8))) short s16x8;
typedef __attribute__((ext_vector_type(8))) __bf16 bf16x8;
typedef __attribute__((ext_vector_type(4))) float f32x4;
typedef __attribute__((ext_vector_type(4))) unsigned short u16x4;

__device__ __forceinline__ f32x4 mfma_bf16(s16x8 a, s16x8 b, f32x4 c) {
  return __builtin_amdgcn_mfma_f32_16x16x32_bf16(
      __builtin_bit_cast(bf16x8, a), __builtin_bit_cast(bf16x8, b), c, 0, 0, 0);
}

__device__ __forceinline__ unsigned short f2bf(float f) {
  unsigned int u = __builtin_bit_cast(unsigned int, f);
  unsigned int r = u + 0x7FFFu + ((u >> 16) & 1u);
  return (unsigned short)(r >> 16);
}

// ---------------- fp32 -> bf16 bulk convert (vectorized) -------------------
__global__ __launch_bounds__(256) void f32_to_bf16(const float* __restrict__ in,
                                                   unsigned short* __restrict__ out,
                                                   int n4) {
  int i = blockIdx.x * 256 + threadIdx.x;
  if (i < n4) {
    f32x4 v = ((const f32x4*)in)[i];
    u16x4 o;
    o[0] = f2bf(v[0]); o[1] = f2bf(v[1]); o[2] = f2bf(v[2]); o[3] = f2bf(v[3]);
    ((u16x4*)out)[i] = o;
  }
}

// ---------- weight transpose + convert: in fp32 [K][N] -> out bf16 [N][K] ---
__global__ void transpose_f32_bf16(const float* __restrict__ in,
                                   unsigned short* __restrict__ out, int K, int N) {
  int id = blockIdx.x * 256 + threadIdx.x;
  if (id < K * N) {
    int k = id / N, n = id - k * N;
    out[(size_t)n * K + k] = f2bf(in[id]);
  }
}

// ---------------- direct-global MFMA GEMM, M=8192, N=320 -------------------
// A [M][K] bf16, Wt [N][K] bf16 (pre-transposed). 64x64 block tile,
// 4 waves as 2x2, each wave 32x32 via 2x2 16x16x32 fragments.
// MODE 0: Q proj  -> bf16 dst[((b*8+h)*4096+s)*64 + d] * scale
// MODE 1: K proj  -> bf16 dst[((b*8+h)*4096+s)*64 + d]
// MODE 2: V proj  -> bf16 dst[((b*8+h)*48+d)*4096 + s]   (transposed)
// MODE 3: O proj  -> fp32 dst[m*320+n] + bias[n]
template <int MODE>
__global__ __launch_bounds__(256) void gemm_direct(
    const unsigned short* __restrict__ A, const unsigned short* __restrict__ Wt,
    void* __restrict__ dstv, const float* __restrict__ bias, int K, float scale) {
  const int tid = threadIdx.x;
  const int l = tid & 63, w = tid >> 6;
  const int wm = w >> 1, wn = w & 1;
  const int lr = l & 15, lg = l >> 4;
  const int row0 = blockIdx.x * 64 + wm * 32;
  const int col0 = blockIdx.y * 64 + wn * 32;

  const unsigned short* Ap = A + (size_t)(row0 + lr) * K + lg * 8;
  const unsigned short* Bp = Wt + (size_t)(col0 + lr) * K + lg * 8;

  f32x4 acc[2][2];
#pragma unroll
  for (int i = 0; i < 2; i++)
#pragma unroll
    for (int j = 0; j < 2; j++) acc[i][j] = f32x4{0.f, 0.f, 0.f, 0.f};

  for (int k0 = 0; k0 < K; k0 += 32) {
    s16x8 a0 = *(const s16x8*)(Ap + k0);
    s16x8 a1 = *(const s16x8*)(Ap + (size_t)16 * K + k0);
    s16x8 b0 = *(const s16x8*)(Bp + k0);
    s16x8 b1 = *(const s16x8*)(Bp + (size_t)16 * K + k0);
    acc[0][0] = mfma_bf16(a0, b0, acc[0][0]);
    acc[0][1] = mfma_bf16(a0, b1, acc[0][1]);
    acc[1][0] = mfma_bf16(a1, b0, acc[1][0]);
    acc[1][1] = mfma_bf16(a1, b1, acc[1][1]);
  }

#pragma unroll
  for (int mf = 0; mf < 2; mf++)
#pragma unroll
    for (int nf = 0; nf < 2; nf++)
#pragma unroll
      for (int r = 0; r < 4; r++) {
        int m = row0 + mf * 16 + lg * 4 + r;
        int n = col0 + nf * 16 + lr;
        float v = acc[mf][nf][r];
        if (MODE == 0 || MODE == 1) {
          int b = m >> 12, s = m & 4095;
          int h = n / 40, d = n - h * 40;
          ((unsigned short*)dstv)[((size_t)(b * 8 + h) * 4096 + s) * 64 + d] =
              f2bf(v * scale);
        } else if (MODE == 2) {
          int b = m >> 12, s = m & 4095;
          int h = n / 40, d = n - h * 40;
          ((unsigned short*)dstv)[((size_t)(b * 8 + h) * 48 + d) * 4096 + s] = f2bf(v);
        } else {
          ((float*)dstv)[(size_t)m * 320 + n] = v + bias[n];
        }
      }
}

// ---------------- flash attention ------------------------------------------
// Qh [16][4096][64] (prescaled by scale*log2e, d>=40 zero)
// Kh [16][4096][64] (d>=40 zero), Vt [16][48][4096] (d>=40 zero)
// grid (32, 16); 256 threads; wave w owns q rows [qbase+32w, +32)
__global__ __launch_bounds__(256) void attn_kernel(
    const unsigned short* __restrict__ Qh, const unsigned short* __restrict__ Kh,
    const unsigned short* __restrict__ Vt, unsigned short* __restrict__ AO) {
  __shared__ __align__(16) char kt[8192];       // K tile [64 sk][64 d], swizzled
  __shared__ __align__(16) char vts[6144];      // V tile [48 d][64 sk], swizzled
  __shared__ __align__(16) char pts[4][4096];   // per-wave P [32 s][64 sk]

  const int tid = threadIdx.x;
  const int l = tid & 63, w = tid >> 6;
  const int lr = l & 15, lg = l >> 4;
  const int bh = blockIdx.y;
  const int b = bh >> 3, h = bh & 7;
  const int qbase = blockIdx.x * 128;

  const unsigned short* Qp = Qh + ((size_t)bh * 4096 + qbase + w * 32) * 64;
  const unsigned short* Kp = Kh + (size_t)bh * 4096 * 64;
  const unsigned short* Vp = Vt + (size_t)bh * 48 * 4096;

  // Q fragments, kept in registers for the whole KV loop
  s16x8 q[2][2];
#pragma unroll
  for (int mf = 0; mf < 2; mf++)
#pragma unroll
    for (int kc = 0; kc < 2; kc++)
      q[mf][kc] = *(const s16x8*)(Qp + (mf * 16 + lr) * 64 + kc * 32 + lg * 8);

  f32x4 O[2][3];
  float rm[2][4], rl[2][4];
#pragma unroll
  for (int mf = 0; mf < 2; mf++) {
#pragma unroll
    for (int nf = 0; nf < 3; nf++) O[mf][nf] = f32x4{0.f, 0.f, 0.f, 0.f};
#pragma unroll
    for (int r = 0; r < 4; r++) { rm[mf][r] = -1e30f; rl[mf][r] = 0.f; }
  }

  char* pw = pts[w];

  for (int kb = 0; kb < 4096; kb += 64) {
    __syncthreads();
    // stage K tile (coalesced 1KB/wave reads, swizzled LDS writes)
#pragma unroll
    for (int i = 0; i < 2; i++) {
      int idx = tid + i * 256;
      int row = idx >> 3, ch = idx & 7;
      s16x8 tv = *(const s16x8*)(Kp + (size_t)(kb + row) * 64 + ch * 8);
      *(s16x8*)(kt + ((row * 128 + ch * 16) ^ ((row & 7) << 4))) = tv;
    }
    // stage V tile (48 rows)
#pragma unroll
    for (int i = 0; i < 2; i++) {
      int idx = tid + i * 256;
      if (idx < 384) {
        int row = idx >> 3, ch = idx & 7;
        s16x8 tv = *(const s16x8*)(Vp + (size_t)row * 4096 + kb + ch * 8);
        *(s16x8*)(vts + ((row * 128 + ch * 16) ^ ((row & 7) << 4))) = tv;
      }
    }
    __syncthreads();

#pragma unroll
    for (int mf = 0; mf < 2; mf++) {
      // QK^T: S[m=s][n=sk], 4 sk-fragments x 2 k-chunks
      f32x4 sf[4];
#pragma unroll
      for (int nf = 0; nf < 4; nf++) sf[nf] = f32x4{0.f, 0.f, 0.f, 0.f};
#pragma unroll
      for (int nf = 0; nf < 4; nf++) {
        int krow = nf * 16 + lr;
#pragma unroll
        for (int kc = 0; kc < 2; kc++) {
          s16x8 kf = *(const s16x8*)(
              kt + ((krow * 128 + kc * 64 + lg * 16) ^ ((krow & 7) << 4)));
          sf[nf] = mfma_bf16(q[mf][kc], kf, sf[nf]);
        }
      }
      // online softmax; row r of lane = s_local lg*4+r; cols spread on lr
      float tm[4], ts[4];
#pragma unroll
      for (int r = 0; r < 4; r++)
        tm[r] = fmaxf(fmaxf(sf[0][r], sf[1][r]), fmaxf(sf[2][r], sf[3][r]));
#pragma unroll
      for (int mask = 1; mask <= 8; mask <<= 1)
#pragma unroll
        for (int r = 0; r < 4; r++)
          tm[r] = fmaxf(tm[r], __shfl_xor(tm[r], mask, 64));
#pragma unroll
      for (int r = 0; r < 4; r++) {
        float mn = fmaxf(rm[mf][r], tm[r]);
        float al = exp2f(rm[mf][r] - mn);
        rm[mf][r] = mn;
        rl[mf][r] *= al;
#pragma unroll
        for (int nf = 0; nf < 3; nf++) O[mf][nf][r] *= al;
        ts[r] = 0.f;
      }
#pragma unroll
      for (int nf = 0; nf < 4; nf++)
#pragma unroll
        for (int r = 0; r < 4; r++) {
          float p = exp2f(sf[nf][r] - rm[mf][r]);
          ts[r] += p;
          int srow = lg * 4 + r;
          int sk = nf * 16 + lr;
          *(unsigned short*)(pw + (((mf * 16 + srow) * 128 + sk * 2) ^
                                   ((srow & 7) << 4))) = f2bf(p);
        }
#pragma unroll
      for (int mask = 1; mask <= 8; mask <<= 1)
#pragma unroll
        for (int r = 0; r < 4; r++) ts[r] += __shfl_xor(ts[r], mask, 64);
#pragma unroll
      for (int r = 0; r < 4; r++) rl[mf][r] += ts[r];
    }

    // PV: O[m=s][n=d] += P[s][sk] * V[sk][d] (V read from transposed tile)
#pragma unroll
    for (int kc = 0; kc < 2; kc++) {
      s16x8 pa[2];
#pragma unroll
      for (int mf = 0; mf < 2; mf++)
        pa[mf] = *(const s16x8*)(
            pw + (((mf * 16 + lr) * 128 + kc * 64 + lg * 16) ^ ((lr & 7) << 4)));
#pragma unroll
      for (int nf = 0; nf < 3; nf++) {
        int vrow = nf * 16 + lr;
        s16x8 vb = *(const s16x8*)(
            vts + ((vrow * 128 + kc * 64 + lg * 16) ^ ((vrow & 7) << 4)));
#pragma unroll
        for (int mf = 0; mf < 2; mf++)
          O[mf][nf] = mfma_bf16(pa[mf], vb, O[mf][nf]);
      }
    }
  }

  // epilogue: normalize and write AO [b][s][h*40+d] (bf16 scratch)
#pragma unroll
  for (int mf = 0; mf < 2; mf++) {
    float inv[4];
#pragma unroll
    for (int r = 0; r < 4; r++) inv[r] = 1.f / rl[mf][r];
#pragma unroll
    for (int nf = 0; nf < 3; nf++) {
      int d = nf * 16 + lr;
      if (d < 40) {
#pragma unroll
        for (int r = 0; r < 4; r++) {
          int s = qbase + w * 32 + mf * 16 + lg * 4 + r;
          AO[((size_t)(b * 4096 + s)) * 320 + h * 40 + d] =
              f2bf(O[mf][nf][r] * inv[r]);
        }
      }
    }
  }
}

// ---------------------------------------------------------------------------
extern "C" void kernel_launch(void* const* d_in, const int* in_sizes, int n_in,
                              void* d_out, int out_size, void* d_ws,
                              size_t ws_size, hipStream_t stream) {
  const float* x    = (const float*)d_in[0];
  const float* cond = (const float*)d_in[1];
  const float* Wq   = (const float*)d_in[2];
  const float* Wk   = (const float*)d_in[3];
  const float* Wv   = (const float*)d_in[4];
  const float* Wo   = (const float*)d_in[5];
  const float* bo   = (const float*)d_in[6];

  char* ws = (char*)d_ws;
  unsigned short* xb    = (unsigned short*)(ws + 0);          // 8192*320*2   = 5,242,880
  unsigned short* condb = (unsigned short*)(ws + 5242880);    // 8192*768*2   = 12,582,912
  unsigned short* WtQ   = (unsigned short*)(ws + 17825792);   // 320*320*2    = 204,800
  unsigned short* WtK   = (unsigned short*)(ws + 18030592);   // 768*320*2    = 491,520
  unsigned short* WtV   = (unsigned short*)(ws + 18522112);   // 768*320*2    = 491,520
  unsigned short* WtO   = (unsigned short*)(ws + 19013632);   // 320*320*2    = 204,800
  unsigned short* AO    = (unsigned short*)(ws + 19218432);   // 8192*320*2   = 5,242,880
  unsigned short* Qh    = (unsigned short*)(ws + 24461312);   // 16*4096*64*2 = 8,388,608
  unsigned short* Kh    = (unsigned short*)(ws + 32849920);   // 16*4096*64*2 = 8,388,608
  unsigned short* Vt    = (unsigned short*)(ws + 41238528);   // 16*48*4096*2 = 6,291,456
  // total = 47,529,984 bytes

  // zero padded Q/K/V buffers (d>=40 pads must be 0 for MFMA correctness)
  hipMemsetAsync(Qh, 0, 23068672, stream);

  // fp32 -> bf16 converts (x: 2.6M elems, cond: 6.3M elems)
  f32_to_bf16<<<dim3(2560), 256, 0, stream>>>(x, xb, 655360);
  f32_to_bf16<<<dim3(6144), 256, 0, stream>>>(cond, condb, 1572864);

  transpose_f32_bf16<<<dim3(400), 256, 0, stream>>>(Wq, WtQ, 320, 320);
  transpose_f32_bf16<<<dim3(960), 256, 0, stream>>>(Wk, WtK, 768, 320);
  transpose_f32_bf16<<<dim3(960), 256, 0, stream>>>(Wv, WtV, 768, 320);
  transpose_f32_bf16<<<dim3(400), 256, 0, stream>>>(Wo, WtO, 320, 320);

  const float qscale = 1.44269504088896f / sqrtf(40.0f);  // log2(e)/sqrt(Dh)

  gemm_direct<0><<<dim3(128, 5), 256, 0, stream>>>(xb, WtQ, Qh, nullptr, 320, qscale);
  gemm_direct<1><<<dim3(128, 5), 256, 0, stream>>>(condb, WtK, Kh, nullptr, 768, 1.0f);
  gemm_direct<2><<<dim3(128, 5), 256, 0, stream>>>(condb, WtV, Vt, nullptr, 768, 1.0f);

  attn_kernel<<<dim3(32, 16), 256, 0, stream>>>(Qh, Kh, Vt, AO);

  gemm_direct<3><<<dim3(128, 5), 256, 0, stream>>>(AO, WtO, d_out, bo, 320, 1.0f);
}

// Round 8
// 309.406 us; speedup vs baseline: 1.4885x; 1.4885x over previous
//
#include <hip/hip_runtime.h>

typedef __attribute__((ext_vector_type(8))) short s16x8;
typedef __attribute__((ext_vector_type(4))) short s16x4;
typedef __attribute__((ext_vector_type(8))) __bf16 bf16x8;
typedef __attribute__((ext_vector_type(4))) float f32x4;
typedef __attribute__((ext_vector_type(4))) unsigned short u16x4;
typedef __attribute__((ext_vector_type(4))) unsigned int u32x4;

__device__ __forceinline__ f32x4 mfma_bf16(s16x8 a, s16x8 b, f32x4 c) {
  return __builtin_amdgcn_mfma_f32_16x16x32_bf16(
      __builtin_bit_cast(bf16x8, a), __builtin_bit_cast(bf16x8, b), c, 0, 0, 0);
}

__device__ __forceinline__ unsigned short f2bf(float f) {
  unsigned int u = __builtin_bit_cast(unsigned int, f);
  unsigned int r = u + 0x7FFFu + ((u >> 16) & 1u);
  return (unsigned short)(r >> 16);
}

__device__ __forceinline__ unsigned int cvt_pk_bf16(float lo, float hi) {
  unsigned int d;
  asm volatile("v_cvt_pk_bf16_f32 %0, %1, %2" : "=v"(d) : "v"(lo), "v"(hi));
  return d;
}

// ---------------- fp32 -> bf16 bulk convert (vectorized) -------------------
__global__ __launch_bounds__(256) void f32_to_bf16(const float* __restrict__ in,
                                                   unsigned short* __restrict__ out,
                                                   int n4) {
  int i = blockIdx.x * 256 + threadIdx.x;
  if (i < n4) {
    f32x4 v = ((const f32x4*)in)[i];
    u16x4 o;
    o[0] = f2bf(v[0]); o[1] = f2bf(v[1]); o[2] = f2bf(v[2]); o[3] = f2bf(v[3]);
    ((u16x4*)out)[i] = o;
  }
}

// ---------- weight transpose + convert: in fp32 [K][N] -> out bf16 [N][K] ---
__global__ void transpose_f32_bf16(const float* __restrict__ in,
                                   unsigned short* __restrict__ out, int K, int N) {
  int id = blockIdx.x * 256 + threadIdx.x;
  if (id < K * N) {
    int k = id / N, n = id - k * N;
    out[(size_t)n * K + k] = f2bf(in[id]);
  }
}

// ---------------- direct-global MFMA GEMM, M=8192, N=320 -------------------
// A [M][K] bf16, Wt [N][K] bf16 (pre-transposed). 64x64 block tile,
// 4 waves as 2x2, each wave 32x32 via 2x2 16x16x32 fragments.
// MODE 0: Q proj  -> bf16 dst[((b*8+h)*4096+s)*64 + d] * scale
// MODE 1: K proj  -> bf16 dst[((b*8+h)*4096+s)*64 + d]
// MODE 2: V proj  -> bf16 dst[((b*8+h)*48+d)*4096 + s]   (transposed)
// MODE 3: O proj  -> fp32 dst[m*320+n] + bias[n]
template <int MODE>
__global__ __launch_bounds__(256) void gemm_direct(
    const unsigned short* __restrict__ A, const unsigned short* __restrict__ Wt,
    void* __restrict__ dstv, const float* __restrict__ bias, int K, float scale) {
  const int tid = threadIdx.x;
  const int l = tid & 63, w = tid >> 6;
  const int wm = w >> 1, wn = w & 1;
  const int lr = l & 15, lg = l >> 4;
  const int row0 = blockIdx.x * 64 + wm * 32;
  const int col0 = blockIdx.y * 64 + wn * 32;

  const unsigned short* Ap = A + (size_t)(row0 + lr) * K + lg * 8;
  const unsigned short* Bp = Wt + (size_t)(col0 + lr) * K + lg * 8;

  f32x4 acc[2][2];
#pragma unroll
  for (int i = 0; i < 2; i++)
#pragma unroll
    for (int j = 0; j < 2; j++) acc[i][j] = f32x4{0.f, 0.f, 0.f, 0.f};

  for (int k0 = 0; k0 < K; k0 += 32) {
    s16x8 a0 = *(const s16x8*)(Ap + k0);
    s16x8 a1 = *(const s16x8*)(Ap + (size_t)16 * K + k0);
    s16x8 b0 = *(const s16x8*)(Bp + k0);
    s16x8 b1 = *(const s16x8*)(Bp + (size_t)16 * K + k0);
    acc[0][0] = mfma_bf16(a0, b0, acc[0][0]);
    acc[0][1] = mfma_bf16(a0, b1, acc[0][1]);
    acc[1][0] = mfma_bf16(a1, b0, acc[1][0]);
    acc[1][1] = mfma_bf16(a1, b1, acc[1][1]);
  }

#pragma unroll
  for (int mf = 0; mf < 2; mf++)
#pragma unroll
    for (int nf = 0; nf < 2; nf++)
#pragma unroll
      for (int r = 0; r < 4; r++) {
        int m = row0 + mf * 16 + lg * 4 + r;
        int n = col0 + nf * 16 + lr;
        float v = acc[mf][nf][r];
        if (MODE == 0 || MODE == 1) {
          int b = m >> 12, s = m & 4095;
          int h = n / 40, d = n - h * 40;
          ((unsigned short*)dstv)[((size_t)(b * 8 + h) * 4096 + s) * 64 + d] =
              f2bf(v * scale);
        } else if (MODE == 2) {
          int b = m >> 12, s = m & 4095;
          int h = n / 40, d = n - h * 40;
          ((unsigned short*)dstv)[((size_t)(b * 8 + h) * 48 + d) * 4096 + s] = f2bf(v);
        } else {
          ((float*)dstv)[(size_t)m * 320 + n] = v + bias[n];
        }
      }
}

// ---------------- flash attention, swapped-QK^T (lane-local softmax) -------
// Qh [16][4096][64] (prescaled by scale*log2e, d>=40 zero)
// Kh [16][4096][64] (d>=40 zero), Vt [16][48][4096] (d>=40 zero)
// grid (32, 16); 512 threads = 8 waves; wave w owns q rows [qbase+16w, +16)
// Per KV tile: S^T = mfma(A=K, B=Q)  -> lane holds 16 scores of ONE q row
// (q = lane&15, kv = nf*16 + (lane>>4)*4 + r).  Softmax: 15 in-reg ops +
// 2 shuffles.  P stays in registers (cvt_pk to bf16); PV computes
// O^T = mfma(A=V^T, B=P^T) with a k-axis permutation matching P's natural
// register layout (A side absorbs it via two ds_read_b64 per fragment).
__global__ __launch_bounds__(512) void attn_kernel(
    const unsigned short* __restrict__ Qh, const unsigned short* __restrict__ Kh,
    const unsigned short* __restrict__ Vt, unsigned short* __restrict__ AO) {
  __shared__ __align__(16) char kt[8192];   // K tile [64 kv][64 d], swizzled
  __shared__ __align__(16) char vts[6144];  // V^T tile [48 d][64 kv], swizzled

  const int tid = threadIdx.x;
  const int l = tid & 63, w = tid >> 6;
  const int lr = l & 15, lg = l >> 4;
  const int bh = blockIdx.y;
  const int b = bh >> 3, h = bh & 7;
  const int qbase = blockIdx.x * 128;
  const int qrow = qbase + w * 16 + lr;

  const unsigned short* Qp = Qh + ((size_t)bh * 4096 + qbase + w * 16) * 64;
  const unsigned short* Kp = Kh + (size_t)bh * 4096 * 64;
  const unsigned short* Vp = Vt + (size_t)bh * 48 * 4096;

  // Q as MFMA B-operand: B[n=q=lr][k=d=kc*32+lg*8+j]
  s16x8 q0 = *(const s16x8*)(Qp + lr * 64 + lg * 8);
  s16x8 q1 = *(const s16x8*)(Qp + lr * 64 + 32 + lg * 8);

  f32x4 O[3];  // O^T[d = nf*16 + lg*4 + r][q = lr]
#pragma unroll
  for (int nf = 0; nf < 3; nf++) O[nf] = f32x4{0.f, 0.f, 0.f, 0.f};
  float rm = -1e30f, rl = 0.f;

  for (int kb = 0; kb < 4096; kb += 64) {
    __syncthreads();
    // stage K tile: 512 threads x 16B = 8KB in one shot
    {
      int row = tid >> 3, ch = tid & 7;
      s16x8 tv = *(const s16x8*)(Kp + (size_t)(kb + row) * 64 + ch * 8);
      *(s16x8*)(kt + ((row * 128 + ch * 16) ^ ((row & 7) << 4))) = tv;
    }
    // stage V^T tile: 48 rows x 128B
    if (tid < 384) {
      int row = tid >> 3, ch = tid & 7;
      s16x8 tv = *(const s16x8*)(Vp + (size_t)row * 4096 + kb + ch * 8);
      *(s16x8*)(vts + ((row * 128 + ch * 16) ^ ((row & 7) << 4))) = tv;
    }
    __syncthreads();

    // ---- QK^T (swapped): sf[nf] = S^T[kv-block nf][q] ----
    f32x4 sf[4];
#pragma unroll
    for (int nf = 0; nf < 4; nf++) sf[nf] = f32x4{0.f, 0.f, 0.f, 0.f};
#pragma unroll
    for (int nf = 0; nf < 4; nf++) {
      int krow = nf * 16 + lr;
      s16x8 kf0 = *(const s16x8*)(kt + ((krow * 128 + lg * 16) ^ ((krow & 7) << 4)));
      s16x8 kf1 = *(const s16x8*)(kt + ((krow * 128 + 64 + lg * 16) ^ ((krow & 7) << 4)));
      sf[nf] = mfma_bf16(kf0, q0, sf[nf]);
      sf[nf] = mfma_bf16(kf1, q1, sf[nf]);
    }

    // ---- online softmax, lane-local (q = lr) ----
    float tm = fmaxf(fmaxf(fmaxf(sf[0][0], sf[0][1]), fmaxf(sf[0][2], sf[0][3])),
                     fmaxf(fmaxf(sf[1][0], sf[1][1]), fmaxf(sf[1][2], sf[1][3])));
    tm = fmaxf(tm, fmaxf(fmaxf(fmaxf(sf[2][0], sf[2][1]), fmaxf(sf[2][2], sf[2][3])),
                         fmaxf(fmaxf(sf[3][0], sf[3][1]), fmaxf(sf[3][2], sf[3][3]))));
    tm = fmaxf(tm, __shfl_xor(tm, 16, 64));
    tm = fmaxf(tm, __shfl_xor(tm, 32, 64));
    float mn = fmaxf(rm, tm);
    float al = __builtin_amdgcn_exp2f(rm - mn);
    rm = mn;
    rl *= al;
#pragma unroll
    for (int nf = 0; nf < 3; nf++) {
#pragma unroll
      for (int r = 0; r < 4; r++) O[nf][r] *= al;
    }
    float ts = 0.f;
    unsigned int pk[4][2];
#pragma unroll
    for (int nf = 0; nf < 4; nf++) {
      float p0 = __builtin_amdgcn_exp2f(sf[nf][0] - rm);
      float p1 = __builtin_amdgcn_exp2f(sf[nf][1] - rm);
      float p2 = __builtin_amdgcn_exp2f(sf[nf][2] - rm);
      float p3 = __builtin_amdgcn_exp2f(sf[nf][3] - rm);
      ts += (p0 + p1) + (p2 + p3);
      pk[nf][0] = cvt_pk_bf16(p0, p1);
      pk[nf][1] = cvt_pk_bf16(p2, p3);
    }
    ts += __shfl_xor(ts, 16, 64);
    ts += __shfl_xor(ts, 32, 64);
    rl += ts;

    // ---- PV: O^T += V^T * P^T (k-axis permuted to match P layout) ----
#pragma unroll
    for (int c = 0; c < 2; c++) {
      u32x4 bu = {pk[2 * c][0], pk[2 * c][1], pk[2 * c + 1][0], pk[2 * c + 1][1]};
      s16x8 bfrag = __builtin_bit_cast(s16x8, bu);
#pragma unroll
      for (int nf = 0; nf < 3; nf++) {
        int row = nf * 16 + lr;
        int base = row * 128 + c * 64 + lg * 8;
        int swz = (row & 7) << 4;
        s16x4 a0 = *(const s16x4*)(vts + ((base) ^ swz));
        s16x4 a1 = *(const s16x4*)(vts + ((base + 32) ^ swz));
        s16x8 afrag = {a0[0], a0[1], a0[2], a0[3], a1[0], a1[1], a1[2], a1[3]};
        O[nf] = mfma_bf16(afrag, bfrag, O[nf]);
      }
    }
  }

  // ---- epilogue: O^T/rl -> AO[b][s][h*40+d] ----
  float inv = 1.f / rl;
#pragma unroll
  for (int nf = 0; nf < 3; nf++) {
#pragma unroll
    for (int r = 0; r < 4; r++) {
      int d = nf * 16 + lg * 4 + r;
      if (d < 40) {
        AO[((size_t)(b * 4096 + qrow)) * 320 + h * 40 + d] = f2bf(O[nf][r] * inv);
      }
    }
  }
}

// ---------------------------------------------------------------------------
extern "C" void kernel_launch(void* const* d_in, const int* in_sizes, int n_in,
                              void* d_out, int out_size, void* d_ws,
                              size_t ws_size, hipStream_t stream) {
  const float* x    = (const float*)d_in[0];
  const float* cond = (const float*)d_in[1];
  const float* Wq   = (const float*)d_in[2];
  const float* Wk   = (const float*)d_in[3];
  const float* Wv   = (const float*)d_in[4];
  const float* Wo   = (const float*)d_in[5];
  const float* bo   = (const float*)d_in[6];

  char* ws = (char*)d_ws;
  unsigned short* xb    = (unsigned short*)(ws + 0);          // 8192*320*2   = 5,242,880
  unsigned short* condb = (unsigned short*)(ws + 5242880);    // 8192*768*2   = 12,582,912
  unsigned short* WtQ   = (unsigned short*)(ws + 17825792);   // 320*320*2    = 204,800
  unsigned short* WtK   = (unsigned short*)(ws + 18030592);   // 768*320*2    = 491,520
  unsigned short* WtV   = (unsigned short*)(ws + 18522112);   // 768*320*2    = 491,520
  unsigned short* WtO   = (unsigned short*)(ws + 19013632);   // 320*320*2    = 204,800
  unsigned short* AO    = (unsigned short*)(ws + 19218432);   // 8192*320*2   = 5,242,880
  unsigned short* Qh    = (unsigned short*)(ws + 24461312);   // 16*4096*64*2 = 8,388,608
  unsigned short* Kh    = (unsigned short*)(ws + 32849920);   // 16*4096*64*2 = 8,388,608
  unsigned short* Vt    = (unsigned short*)(ws + 41238528);   // 16*48*4096*2 = 6,291,456
  // total = 47,529,984 bytes

  // zero padded Q/K/V buffers (d>=40 pads must be 0 for MFMA correctness)
  hipMemsetAsync(Qh, 0, 23068672, stream);

  // fp32 -> bf16 converts (x: 2.6M elems, cond: 6.3M elems)
  f32_to_bf16<<<dim3(2560), 256, 0, stream>>>(x, xb, 655360);
  f32_to_bf16<<<dim3(6144), 256, 0, stream>>>(cond, condb, 1572864);

  transpose_f32_bf16<<<dim3(400), 256, 0, stream>>>(Wq, WtQ, 320, 320);
  transpose_f32_bf16<<<dim3(960), 256, 0, stream>>>(Wk, WtK, 768, 320);
  transpose_f32_bf16<<<dim3(960), 256, 0, stream>>>(Wv, WtV, 768, 320);
  transpose_f32_bf16<<<dim3(400), 256, 0, stream>>>(Wo, WtO, 320, 320);

  const float qscale = 1.44269504088896f / sqrtf(40.0f);  // log2(e)/sqrt(Dh)

  gemm_direct<0><<<dim3(128, 5), 256, 0, stream>>>(xb, WtQ, Qh, nullptr, 320, qscale);
  gemm_direct<1><<<dim3(128, 5), 256, 0, stream>>>(condb, WtK, Kh, nullptr, 768, 1.0f);
  gemm_direct<2><<<dim3(128, 5), 256, 0, stream>>>(condb, WtV, Vt, nullptr, 768, 1.0f);

  attn_kernel<<<dim3(32, 16), 512, 0, stream>>>(Qh, Kh, Vt, AO);

  gemm_direct<3><<<dim3(128, 5), 256, 0, stream>>>(AO, WtO, d_out, bo, 320, 1.0f);
}

// Round 10
// 294.893 us; speedup vs baseline: 1.5618x; 1.0492x over previous
//
#include <hip/hip_runtime.h>

typedef __attribute__((ext_vector_type(8))) short s16x8;
typedef __attribute__((ext_vector_type(4))) short s16x4;
typedef __attribute__((ext_vector_type(8))) __bf16 bf16x8;
typedef __attribute__((ext_vector_type(4))) float f32x4;
typedef __attribute__((ext_vector_type(4))) unsigned short u16x4;
typedef __attribute__((ext_vector_type(4))) unsigned int u32x4;

__device__ __forceinline__ f32x4 mfma_bf16(s16x8 a, s16x8 b, f32x4 c) {
  return __builtin_amdgcn_mfma_f32_16x16x32_bf16(
      __builtin_bit_cast(bf16x8, a), __builtin_bit_cast(bf16x8, b), c, 0, 0, 0);
}

__device__ __forceinline__ unsigned short f2bf(float f) {
  unsigned int u = __builtin_bit_cast(unsigned int, f);
  unsigned int r = u + 0x7FFFu + ((u >> 16) & 1u);
  return (unsigned short)(r >> 16);
}

__device__ __forceinline__ unsigned int cvt_pk_bf16(float lo, float hi) {
  unsigned int d;
  asm volatile("v_cvt_pk_bf16_f32 %0, %1, %2" : "=v"(d) : "v"(lo), "v"(hi));
  return d;
}

// ---------------- fp32 -> bf16 bulk convert (vectorized) -------------------
__global__ __launch_bounds__(256) void f32_to_bf16(const float* __restrict__ in,
                                                   unsigned short* __restrict__ out,
                                                   int n4) {
  int i = blockIdx.x * 256 + threadIdx.x;
  if (i < n4) {
    f32x4 v = ((const f32x4*)in)[i];
    u16x4 o;
    o[0] = f2bf(v[0]); o[1] = f2bf(v[1]); o[2] = f2bf(v[2]); o[3] = f2bf(v[3]);
    ((u16x4*)out)[i] = o;
  }
}

// ---------- weight transpose + convert: in fp32 [K][N] -> out bf16 [N][K] ---
__global__ void transpose_f32_bf16(const float* __restrict__ in,
                                   unsigned short* __restrict__ out, int K, int N) {
  int id = blockIdx.x * 256 + threadIdx.x;
  if (id < K * N) {
    int k = id / N, n = id - k * N;
    out[(size_t)n * K + k] = f2bf(in[id]);
  }
}

// ---------------- direct-global MFMA GEMM, M=8192, N=320 -------------------
// A [M][K] bf16, Wt [N][K] bf16 (pre-transposed). 64x64 block tile,
// 4 waves as 2x2, each wave 32x32 via 2x2 16x16x32 fragments.
// K is a template param: k-loop fully unrolls with a depth-2 register
// pipeline (load batch i+1 while MFMAing batch i) to hide L2 latency.
// MODE 0: Q proj  -> bf16 dst[((b*8+h)*4096+s)*64 + d] * scale
// MODE 1: K proj  -> bf16 dst[((b*8+h)*4096+s)*64 + d]
// MODE 2: V proj  -> bf16 dst[((b*8+h)*48+d)*4096 + s]   (transposed)
// MODE 3: O proj  -> fp32 dst[m*320+n] + bias[n]
template <int MODE, int K>
__global__ __launch_bounds__(256) void gemm_direct(
    const unsigned short* __restrict__ A, const unsigned short* __restrict__ Wt,
    void* __restrict__ dstv, const float* __restrict__ bias, float scale) {
  const int tid = threadIdx.x;
  const int l = tid & 63, w = tid >> 6;
  const int wm = w >> 1, wn = w & 1;
  const int lr = l & 15, lg = l >> 4;
  const int row0 = blockIdx.x * 64 + wm * 32;
  const int col0 = blockIdx.y * 64 + wn * 32;

  const unsigned short* Ap = A + (size_t)(row0 + lr) * K + lg * 8;
  const unsigned short* Bp = Wt + (size_t)(col0 + lr) * K + lg * 8;

  f32x4 acc[2][2];
#pragma unroll
  for (int i = 0; i < 2; i++)
#pragma unroll
    for (int j = 0; j < 2; j++) acc[i][j] = f32x4{0.f, 0.f, 0.f, 0.f};

  constexpr int NB = K / 32;
  s16x8 a0[2], a1[2], b0[2], b1[2];
  a0[0] = *(const s16x8*)(Ap);
  a1[0] = *(const s16x8*)(Ap + (size_t)16 * K);
  b0[0] = *(const s16x8*)(Bp);
  b1[0] = *(const s16x8*)(Bp + (size_t)16 * K);

#pragma unroll
  for (int i = 0; i < NB; i++) {
    const int cur = i & 1, nxt = cur ^ 1;
    if (i + 1 < NB) {
      const int k = (i + 1) * 32;
      a0[nxt] = *(const s16x8*)(Ap + k);
      a1[nxt] = *(const s16x8*)(Ap + (size_t)16 * K + k);
      b0[nxt] = *(const s16x8*)(Bp + k);
      b1[nxt] = *(const s16x8*)(Bp + (size_t)16 * K + k);
    }
    acc[0][0] = mfma_bf16(a0[cur], b0[cur], acc[0][0]);
    acc[0][1] = mfma_bf16(a0[cur], b1[cur], acc[0][1]);
    acc[1][0] = mfma_bf16(a1[cur], b0[cur], acc[1][0]);
    acc[1][1] = mfma_bf16(a1[cur], b1[cur], acc[1][1]);
  }

#pragma unroll
  for (int mf = 0; mf < 2; mf++)
#pragma unroll
    for (int nf = 0; nf < 2; nf++)
#pragma unroll
      for (int r = 0; r < 4; r++) {
        int m = row0 + mf * 16 + lg * 4 + r;
        int n = col0 + nf * 16 + lr;
        float v = acc[mf][nf][r];
        if (MODE == 0 || MODE == 1) {
          int b = m >> 12, s = m & 4095;
          int h = n / 40, d = n - h * 40;
          ((unsigned short*)dstv)[((size_t)(b * 8 + h) * 4096 + s) * 64 + d] =
              f2bf(v * scale);
        } else if (MODE == 2) {
          int b = m >> 12, s = m & 4095;
          int h = n / 40, d = n - h * 40;
          ((unsigned short*)dstv)[((size_t)(b * 8 + h) * 48 + d) * 4096 + s] = f2bf(v);
        } else {
          ((float*)dstv)[(size_t)m * 320 + n] = v + bias[n];
        }
      }
}

// ---------------- flash attention, swapped-QK^T (lane-local softmax) -------
// Qh [16][4096][64] (prescaled by scale*log2e, d>=40 zero)
// Kh [16][4096][64] (d>=40 zero), Vt [16][48][4096] (d>=40 zero)
// grid (32, 16); 512 threads = 8 waves; wave w owns q rows [qbase+16w, +16)
// S^T = mfma(A=K, B=Q): lane-local softmax (q=lane&15), P in registers,
// PV via k-axis-permuted O^T = mfma(A=V^T, B=P^T).
// This round: T14 async-STAGE (issue t+1 loads at top of compute(t),
// ds_write after read-barrier), T5 setprio around MFMA clusters, T13
// defer-max (exact: skipped rescale is multiply-by-exp2(0)=1).
__global__ __launch_bounds__(512) void attn_kernel(
    const unsigned short* __restrict__ Qh, const unsigned short* __restrict__ Kh,
    const unsigned short* __restrict__ Vt, unsigned short* __restrict__ AO) {
  __shared__ __align__(16) char kt[8192];   // K tile [64 kv][64 d], swizzled
  __shared__ __align__(16) char vts[6144];  // V^T tile [48 d][64 kv], swizzled

  const int tid = threadIdx.x;
  const int l = tid & 63, w = tid >> 6;
  const int lr = l & 15, lg = l >> 4;
  const int bh = blockIdx.y;
  const int b = bh >> 3, h = bh & 7;
  const int qbase = blockIdx.x * 128;
  const int qrow = qbase + w * 16 + lr;

  const unsigned short* Qp = Qh + ((size_t)bh * 4096 + qbase + w * 16) * 64;
  const unsigned short* Kp = Kh + (size_t)bh * 4096 * 64;
  const unsigned short* Vp = Vt + (size_t)bh * 48 * 4096;

  // staging coordinates (fixed per thread)
  const int srow = tid >> 3, sch = tid & 7;
  const bool hasv = (tid < 384);
  const int kofs = ((srow * 128 + sch * 16) ^ ((srow & 7) << 4));

  // Q as MFMA B-operand: B[n=q=lr][k=d=kc*32+lg*8+j]
  s16x8 q0 = *(const s16x8*)(Qp + lr * 64 + lg * 8);
  s16x8 q1 = *(const s16x8*)(Qp + lr * 64 + 32 + lg * 8);

  f32x4 O[3];  // O^T[d = nf*16 + lg*4 + r][q = lr]
#pragma unroll
  for (int nf = 0; nf < 3; nf++) O[nf] = f32x4{0.f, 0.f, 0.f, 0.f};
  float rm = -1e30f, rl = 0.f;

  // prologue: stage tile 0
  s16x8 kreg = *(const s16x8*)(Kp + (size_t)srow * 64 + sch * 8);
  s16x8 vreg;
  if (hasv) vreg = *(const s16x8*)(Vp + (size_t)srow * 4096 + sch * 8);
  *(s16x8*)(kt + kofs) = kreg;
  if (hasv) *(s16x8*)(vts + kofs) = vreg;
  __syncthreads();

  for (int kb = 0; kb < 4096; kb += 64) {
    // T14: issue next tile's global loads now; latency hides under compute
    if (kb + 64 < 4096) {
      kreg = *(const s16x8*)(Kp + (size_t)(kb + 64 + srow) * 64 + sch * 8);
      if (hasv) vreg = *(const s16x8*)(Vp + (size_t)srow * 4096 + kb + 64 + sch * 8);
    }

    // ---- QK^T (swapped): sf[nf] = S^T[kv-block nf][q] ----
    f32x4 sf[4];
#pragma unroll
    for (int nf = 0; nf < 4; nf++) sf[nf] = f32x4{0.f, 0.f, 0.f, 0.f};
    __builtin_amdgcn_s_setprio(1);
#pragma unroll
    for (int nf = 0; nf < 4; nf++) {
      int krow = nf * 16 + lr;
      s16x8 kf0 = *(const s16x8*)(kt + ((krow * 128 + lg * 16) ^ ((krow & 7) << 4)));
      s16x8 kf1 = *(const s16x8*)(kt + ((krow * 128 + 64 + lg * 16) ^ ((krow & 7) << 4)));
      sf[nf] = mfma_bf16(kf0, q0, sf[nf]);
      sf[nf] = mfma_bf16(kf1, q1, sf[nf]);
    }
    __builtin_amdgcn_s_setprio(0);

    // ---- online softmax, lane-local (q = lr) ----
    float tm = fmaxf(fmaxf(fmaxf(sf[0][0], sf[0][1]), fmaxf(sf[0][2], sf[0][3])),
                     fmaxf(fmaxf(sf[1][0], sf[1][1]), fmaxf(sf[1][2], sf[1][3])));
    tm = fmaxf(tm, fmaxf(fmaxf(fmaxf(sf[2][0], sf[2][1]), fmaxf(sf[2][2], sf[2][3])),
                         fmaxf(fmaxf(sf[3][0], sf[3][1]), fmaxf(sf[3][2], sf[3][3]))));
    tm = fmaxf(tm, __shfl_xor(tm, 16, 64));
    tm = fmaxf(tm, __shfl_xor(tm, 32, 64));
    // T13 defer-max: if no lane's max grew, rescale factor is exp2(0)=1 -> skip
    if (!__all(tm <= rm)) {
      float mn = fmaxf(rm, tm);
      float al = __builtin_amdgcn_exp2f(rm - mn);
      rm = mn;
      rl *= al;
#pragma unroll
      for (int nf = 0; nf < 3; nf++) {
#pragma unroll
        for (int r = 0; r < 4; r++) O[nf][r] *= al;
      }
    }
    float ts = 0.f;
    unsigned int pk[4][2];
#pragma unroll
    for (int nf = 0; nf < 4; nf++) {
      float p0 = __builtin_amdgcn_exp2f(sf[nf][0] - rm);
      float p1 = __builtin_amdgcn_exp2f(sf[nf][1] - rm);
      float p2 = __builtin_amdgcn_exp2f(sf[nf][2] - rm);
      float p3 = __builtin_amdgcn_exp2f(sf[nf][3] - rm);
      ts += (p0 + p1) + (p2 + p3);
      pk[nf][0] = cvt_pk_bf16(p0, p1);
      pk[nf][1] = cvt_pk_bf16(p2, p3);
    }
    ts += __shfl_xor(ts, 16, 64);
    ts += __shfl_xor(ts, 32, 64);
    rl += ts;

    // ---- PV: O^T += V^T * P^T (k-axis permuted to match P layout) ----
    __builtin_amdgcn_s_setprio(1);
#pragma unroll
    for (int c = 0; c < 2; c++) {
      u32x4 bu = {pk[2 * c][0], pk[2 * c][1], pk[2 * c + 1][0], pk[2 * c + 1][1]};
      s16x8 bfrag = __builtin_bit_cast(s16x8, bu);
#pragma unroll
      for (int nf = 0; nf < 3; nf++) {
        int row = nf * 16 + lr;
        int base = row * 128 + c * 64 + lg * 8;
        int swz = (row & 7) << 4;
        s16x4 a0 = *(const s16x4*)(vts + ((base) ^ swz));
        s16x4 a1 = *(const s16x4*)(vts + ((base + 32) ^ swz));
        s16x8 afrag = {a0[0], a0[1], a0[2], a0[3], a1[0], a1[1], a1[2], a1[3]};
        O[nf] = mfma_bf16(afrag, bfrag, O[nf]);
      }
    }
    __builtin_amdgcn_s_setprio(0);

    // T14 write-late: all LDS reads of this tile done -> barrier -> overwrite
    __syncthreads();
    if (kb + 64 < 4096) {
      *(s16x8*)(kt + kofs) = kreg;
      if (hasv) *(s16x8*)(vts + kofs) = vreg;
    }
    __syncthreads();
  }

  // ---- epilogue: O^T/rl -> AO[b][s][h*40+d] ----
  float inv = 1.f / rl;
#pragma unroll
  for (int nf = 0; nf < 3; nf++) {
#pragma unroll
    for (int r = 0; r < 4; r++) {
      int d = nf * 16 + lg * 4 + r;
      if (d < 40) {
        AO[((size_t)(b * 4096 + qrow)) * 320 + h * 40 + d] = f2bf(O[nf][r] * inv);
      }
    }
  }
}

// ---------------------------------------------------------------------------
extern "C" void kernel_launch(void* const* d_in, const int* in_sizes, int n_in,
                              void* d_out, int out_size, void* d_ws,
                              size_t ws_size, hipStream_t stream) {
  const float* x    = (const float*)d_in[0];
  const float* cond = (const float*)d_in[1];
  const float* Wq   = (const float*)d_in[2];
  const float* Wk   = (const float*)d_in[3];
  const float* Wv   = (const float*)d_in[4];
  const float* Wo   = (const float*)d_in[5];
  const float* bo   = (const float*)d_in[6];

  char* ws = (char*)d_ws;
  unsigned short* xb    = (unsigned short*)(ws + 0);          // 8192*320*2   = 5,242,880
  unsigned short* condb = (unsigned short*)(ws + 5242880);    // 8192*768*2   = 12,582,912
  unsigned short* WtQ   = (unsigned short*)(ws + 17825792);   // 320*320*2    = 204,800
  unsigned short* WtK   = (unsigned short*)(ws + 18030592);   // 768*320*2    = 491,520
  unsigned short* WtV   = (unsigned short*)(ws + 18522112);   // 768*320*2    = 491,520
  unsigned short* WtO   = (unsigned short*)(ws + 19013632);   // 320*320*2    = 204,800
  unsigned short* AO    = (unsigned short*)(ws + 19218432);   // 8192*320*2   = 5,242,880
  unsigned short* Qh    = (unsigned short*)(ws + 24461312);   // 16*4096*64*2 = 8,388,608
  unsigned short* Kh    = (unsigned short*)(ws + 32849920);   // 16*4096*64*2 = 8,388,608
  unsigned short* Vt    = (unsigned short*)(ws + 41238528);   // 16*48*4096*2 = 6,291,456
  // total = 47,529,984 bytes

  // zero padded Q/K/V buffers (d>=40 pads must be 0 for MFMA correctness)
  hipMemsetAsync(Qh, 0, 23068672, stream);

  // fp32 -> bf16 converts (x: 2.6M elems, cond: 6.3M elems)
  f32_to_bf16<<<dim3(2560), 256, 0, stream>>>(x, xb, 655360);
  f32_to_bf16<<<dim3(6144), 256, 0, stream>>>(cond, condb, 1572864);

  transpose_f32_bf16<<<dim3(400), 256, 0, stream>>>(Wq, WtQ, 320, 320);
  transpose_f32_bf16<<<dim3(960), 256, 0, stream>>>(Wk, WtK, 768, 320);
  transpose_f32_bf16<<<dim3(960), 256, 0, stream>>>(Wv, WtV, 768, 320);
  transpose_f32_bf16<<<dim3(400), 256, 0, stream>>>(Wo, WtO, 320, 320);

  const float qscale = 1.44269504088896f / sqrtf(40.0f);  // log2(e)/sqrt(Dh)

  gemm_direct<0, 320><<<dim3(128, 5), 256, 0, stream>>>(xb, WtQ, Qh, nullptr, qscale);
  gemm_direct<1, 768><<<dim3(128, 5), 256, 0, stream>>>(condb, WtK, Kh, nullptr, 1.0f);
  gemm_direct<2, 768><<<dim3(128, 5), 256, 0, stream>>>(condb, WtV, Vt, nullptr, 1.0f);

  attn_kernel<<<dim3(32, 16), 512, 0, stream>>>(Qh, Kh, Vt, AO);

  gemm_direct<3, 320><<<dim3(128, 5), 256, 0, stream>>>(AO, WtO, d_out, bo, 1.0f);
}

// Round 11
// 274.545 us; speedup vs baseline: 1.6775x; 1.0741x over previous
//
#include <hip/hip_runtime.h>

typedef __attribute__((ext_vector_type(8))) short s16x8;
typedef __attribute__((ext_vector_type(8))) __bf16 bf16x8;
typedef __attribute__((ext_vector_type(4))) float f32x4;
typedef __attribute__((ext_vector_type(4))) unsigned short u16x4;
typedef __attribute__((ext_vector_type(4))) unsigned int u32x4;

__device__ __forceinline__ f32x4 mfma_bf16(s16x8 a, s16x8 b, f32x4 c) {
  return __builtin_amdgcn_mfma_f32_16x16x32_bf16(
      __builtin_bit_cast(bf16x8, a), __builtin_bit_cast(bf16x8, b), c, 0, 0, 0);
}

__device__ __forceinline__ unsigned short f2bf(float f) {
  unsigned int u = __builtin_bit_cast(unsigned int, f);
  unsigned int r = u + 0x7FFFu + ((u >> 16) & 1u);
  return (unsigned short)(r >> 16);
}

__device__ __forceinline__ unsigned int cvt_pk_bf16(float lo, float hi) {
  unsigned int d;
  asm volatile("v_cvt_pk_bf16_f32 %0, %1, %2" : "=v"(d) : "v"(lo), "v"(hi));
  return d;
}

// ---------------- fused fp32 -> bf16 convert for x and cond ----------------
__global__ __launch_bounds__(256) void convert_all(const float* __restrict__ x,
                                                   const float* __restrict__ cond,
                                                   unsigned short* __restrict__ xb,
                                                   unsigned short* __restrict__ condb) {
  int i = blockIdx.x * 256 + threadIdx.x;
  const float* in;
  unsigned short* out;
  if (i < 655360) {
    in = x; out = xb;
  } else {
    i -= 655360;
    if (i >= 1572864) return;
    in = cond; out = condb;
  }
  f32x4 v = ((const f32x4*)in)[i];
  u16x4 o;
  o[0] = f2bf(v[0]); o[1] = f2bf(v[1]); o[2] = f2bf(v[2]); o[3] = f2bf(v[3]);
  ((u16x4*)out)[i] = o;
}

// ---------- fused weight transpose+convert: fp32 [K][N] -> bf16 [N][K] -----
__global__ void transpose_all(const float* __restrict__ Wq, const float* __restrict__ Wk,
                              const float* __restrict__ Wv, const float* __restrict__ Wo,
                              unsigned short* __restrict__ WtQ, unsigned short* __restrict__ WtK,
                              unsigned short* __restrict__ WtV, unsigned short* __restrict__ WtO) {
  int id = blockIdx.x * 256 + threadIdx.x;
  const float* in;
  unsigned short* out;
  int K;
  if (id < 102400)      { in = Wq; out = WtQ; K = 320; }
  else if (id < 348160) { in = Wk; out = WtK; K = 768; id -= 102400; }
  else if (id < 593920) { in = Wv; out = WtV; K = 768; id -= 348160; }
  else if (id < 696320) { in = Wo; out = WtO; K = 320; id -= 593920; }
  else return;
  int k = id / 320, n = id - k * 320;
  out[(size_t)n * K + k] = f2bf(in[id]);
}

// ---------------- direct-global MFMA GEMM body, M=8192, N=320 --------------
// A [M][K] bf16, Wt [N][K] bf16. 64x64 block tile, 4 waves 2x2, each wave
// 32x32 via 2x2 16x16x32 fragments; depth-2 register pipeline over k.
// MODE 0: Q proj  -> bf16 dst[((b*8+h)*4096+s)*64 + d] * scale
// MODE 1: K proj  -> bf16 dst[((b*8+h)*4096+s)*64 + d]
// MODE 2: V proj  -> bf16 dst[((b*8+h)*48+d)*4096 + s']  (transposed,
//         s' = within-64-tile bit-rotated s so attn PV reads are b128)
// MODE 3: O proj  -> fp32 dst[m*320+n] + bias[n]
template <int MODE, int K>
__device__ __forceinline__ void gemm_body(
    const unsigned short* __restrict__ A, const unsigned short* __restrict__ Wt,
    void* __restrict__ dstv, const float* __restrict__ bias, float scale) {
  const int tid = threadIdx.x;
  const int l = tid & 63, w = tid >> 6;
  const int wm = w >> 1, wn = w & 1;
  const int lr = l & 15, lg = l >> 4;
  const int row0 = blockIdx.x * 64 + wm * 32;
  const int col0 = blockIdx.y * 64 + wn * 32;

  const unsigned short* Ap = A + (size_t)(row0 + lr) * K + lg * 8;
  const unsigned short* Bp = Wt + (size_t)(col0 + lr) * K + lg * 8;

  f32x4 acc[2][2];
#pragma unroll
  for (int i = 0; i < 2; i++)
#pragma unroll
    for (int j = 0; j < 2; j++) acc[i][j] = f32x4{0.f, 0.f, 0.f, 0.f};

  constexpr int NB = K / 32;
  s16x8 a0[2], a1[2], b0[2], b1[2];
  a0[0] = *(const s16x8*)(Ap);
  a1[0] = *(const s16x8*)(Ap + (size_t)16 * K);
  b0[0] = *(const s16x8*)(Bp);
  b1[0] = *(const s16x8*)(Bp + (size_t)16 * K);

#pragma unroll
  for (int i = 0; i < NB; i++) {
    const int cur = i & 1, nxt = cur ^ 1;
    if (i + 1 < NB) {
      const int k = (i + 1) * 32;
      a0[nxt] = *(const s16x8*)(Ap + k);
      a1[nxt] = *(const s16x8*)(Ap + (size_t)16 * K + k);
      b0[nxt] = *(const s16x8*)(Bp + k);
      b1[nxt] = *(const s16x8*)(Bp + (size_t)16 * K + k);
    }
    acc[0][0] = mfma_bf16(a0[cur], b0[cur], acc[0][0]);
    acc[0][1] = mfma_bf16(a0[cur], b1[cur], acc[0][1]);
    acc[1][0] = mfma_bf16(a1[cur], b0[cur], acc[1][0]);
    acc[1][1] = mfma_bf16(a1[cur], b1[cur], acc[1][1]);
  }

#pragma unroll
  for (int mf = 0; mf < 2; mf++)
#pragma unroll
    for (int nf = 0; nf < 2; nf++)
#pragma unroll
      for (int r = 0; r < 4; r++) {
        int m = row0 + mf * 16 + lg * 4 + r;
        int n = col0 + nf * 16 + lr;
        float v = acc[mf][nf][r];
        if (MODE == 0 || MODE == 1) {
          int b = m >> 12, s = m & 4095;
          int h = n / 40, d = n - h * 40;
          ((unsigned short*)dstv)[((size_t)(b * 8 + h) * 4096 + s) * 64 + d] =
              f2bf(v * scale);
        } else if (MODE == 2) {
          int b = m >> 12, s = m & 4095;
          int h = n / 40, d = n - h * 40;
          // within-64-tile perm: bits (c,hi,lg1,lg0,r1,r0) -> (c,lg1,lg0,hi,r1,r0)
          int sp = (s & ~63) | (s & 35) | ((s & 12) << 1) | ((s & 16) >> 2);
          ((unsigned short*)dstv)[((size_t)(b * 8 + h) * 48 + d) * 4096 + sp] = f2bf(v);
        } else {
          ((float*)dstv)[(size_t)m * 320 + n] = v + bias[n];
        }
      }
}

// fused Q/K/V projection: grid (128, 5, 3); z selects mode
__global__ __launch_bounds__(256) void qkv_proj(
    const unsigned short* __restrict__ xb, const unsigned short* __restrict__ condb,
    const unsigned short* __restrict__ WtQ, const unsigned short* __restrict__ WtK,
    const unsigned short* __restrict__ WtV, unsigned short* __restrict__ Qh,
    unsigned short* __restrict__ Kh, unsigned short* __restrict__ Vt, float qscale) {
  if (blockIdx.z == 0)      gemm_body<0, 320>(xb, WtQ, Qh, nullptr, qscale);
  else if (blockIdx.z == 1) gemm_body<1, 768>(condb, WtK, Kh, nullptr, 1.0f);
  else                      gemm_body<2, 768>(condb, WtV, Vt, nullptr, 1.0f);
}

__global__ __launch_bounds__(256) void o_proj(
    const unsigned short* __restrict__ AO, const unsigned short* __restrict__ WtO,
    float* __restrict__ out, const float* __restrict__ bias) {
  gemm_body<3, 320>(AO, WtO, out, bias, 1.0f);
}

// ---------------- flash attention, swapped-QK^T (lane-local softmax) -------
// Qh [16][4096][64] (prescaled by scale*log2e, d>=40 zero)
// Kh [16][4096][64] (d>=40 zero), Vt [16][48][4096] (d>=40 zero, s-permuted)
// grid (32, 16); 512 threads = 8 waves; wave w owns q rows [qbase+16w, +16)
// Double-buffered LDS (1 barrier/iter); PV V-reads are b128 conflict-free
// thanks to the V-proj s-permutation; T14 async-STAGE; T5 setprio; T13
// defer-max (exact).
__global__ __launch_bounds__(512) void attn_kernel(
    const unsigned short* __restrict__ Qh, const unsigned short* __restrict__ Kh,
    const unsigned short* __restrict__ Vt, unsigned short* __restrict__ AO) {
  __shared__ __align__(16) char kt[2][8192];   // K tile [64 kv][64 d], swizzled
  __shared__ __align__(16) char vts[2][6144];  // V^T tile [48 d][64 kv'], swizzled

  const int tid = threadIdx.x;
  const int l = tid & 63, w = tid >> 6;
  const int lr = l & 15, lg = l >> 4;
  const int bh = blockIdx.y;
  const int b = bh >> 3, h = bh & 7;
  const int qbase = blockIdx.x * 128;
  const int qrow = qbase + w * 16 + lr;

  const unsigned short* Qp = Qh + ((size_t)bh * 4096 + qbase + w * 16) * 64;
  const unsigned short* Kp = Kh + (size_t)bh * 4096 * 64;
  const unsigned short* Vp = Vt + (size_t)bh * 48 * 4096;

  // staging coordinates (fixed per thread)
  const int srow = tid >> 3, sch = tid & 7;
  const bool hasv = (tid < 384);
  const int kofs = ((srow * 128 + sch * 16) ^ ((srow & 7) << 4));

  // Q as MFMA B-operand: B[n=q=lr][k=d=kc*32+lg*8+j]
  s16x8 q0 = *(const s16x8*)(Qp + lr * 64 + lg * 8);
  s16x8 q1 = *(const s16x8*)(Qp + lr * 64 + 32 + lg * 8);

  f32x4 O[3];  // O^T[d = nf*16 + lg*4 + r][q = lr]
#pragma unroll
  for (int nf = 0; nf < 3; nf++) O[nf] = f32x4{0.f, 0.f, 0.f, 0.f};
  float rm = -1e30f, rl = 0.f;

  // prologue: stage tile 0 into buffer 0
  s16x8 kreg = *(const s16x8*)(Kp + (size_t)srow * 64 + sch * 8);
  s16x8 vreg;
  if (hasv) vreg = *(const s16x8*)(Vp + (size_t)srow * 4096 + sch * 8);
  *(s16x8*)(kt[0] + kofs) = kreg;
  if (hasv) *(s16x8*)(vts[0] + kofs) = vreg;
  __syncthreads();

  for (int t = 0; t < 64; ++t) {
    const int kb = t * 64;
    const int p = t & 1;
    const char* ktp = kt[p];
    const char* vtp = vts[p];

    // T14: issue next tile's global loads now; latency hides under compute
    if (t + 1 < 64) {
      kreg = *(const s16x8*)(Kp + (size_t)(kb + 64 + srow) * 64 + sch * 8);
      if (hasv) vreg = *(const s16x8*)(Vp + (size_t)srow * 4096 + kb + 64 + sch * 8);
    }

    // ---- QK^T (swapped): sf[nf] = S^T[kv-block nf][q] ----
    f32x4 sf[4];
#pragma unroll
    for (int nf = 0; nf < 4; nf++) sf[nf] = f32x4{0.f, 0.f, 0.f, 0.f};
    __builtin_amdgcn_s_setprio(1);
#pragma unroll
    for (int nf = 0; nf < 4; nf++) {
      int krow = nf * 16 + lr;
      s16x8 kf0 = *(const s16x8*)(ktp + ((krow * 128 + lg * 16) ^ ((krow & 7) << 4)));
      s16x8 kf1 = *(const s16x8*)(ktp + ((krow * 128 + 64 + lg * 16) ^ ((krow & 7) << 4)));
      sf[nf] = mfma_bf16(kf0, q0, sf[nf]);
      sf[nf] = mfma_bf16(kf1, q1, sf[nf]);
    }
    __builtin_amdgcn_s_setprio(0);

    // ---- online softmax, lane-local (q = lr) ----
    float tm = fmaxf(fmaxf(fmaxf(sf[0][0], sf[0][1]), fmaxf(sf[0][2], sf[0][3])),
                     fmaxf(fmaxf(sf[1][0], sf[1][1]), fmaxf(sf[1][2], sf[1][3])));
    tm = fmaxf(tm, fmaxf(fmaxf(fmaxf(sf[2][0], sf[2][1]), fmaxf(sf[2][2], sf[2][3])),
                         fmaxf(fmaxf(sf[3][0], sf[3][1]), fmaxf(sf[3][2], sf[3][3]))));
    tm = fmaxf(tm, __shfl_xor(tm, 16, 64));
    tm = fmaxf(tm, __shfl_xor(tm, 32, 64));
    // T13 defer-max: if no lane's max grew, rescale factor is exp2(0)=1 -> skip
    if (!__all(tm <= rm)) {
      float mn = fmaxf(rm, tm);
      float al = __builtin_amdgcn_exp2f(rm - mn);
      rm = mn;
      rl *= al;
#pragma unroll
      for (int nf = 0; nf < 3; nf++) {
#pragma unroll
        for (int r = 0; r < 4; r++) O[nf][r] *= al;
      }
    }
    float ts = 0.f;
    unsigned int pk[4][2];
#pragma unroll
    for (int nf = 0; nf < 4; nf++) {
      float p0 = __builtin_amdgcn_exp2f(sf[nf][0] - rm);
      float p1 = __builtin_amdgcn_exp2f(sf[nf][1] - rm);
      float p2 = __builtin_amdgcn_exp2f(sf[nf][2] - rm);
      float p3 = __builtin_amdgcn_exp2f(sf[nf][3] - rm);
      ts += (p0 + p1) + (p2 + p3);
      pk[nf][0] = cvt_pk_bf16(p0, p1);
      pk[nf][1] = cvt_pk_bf16(p2, p3);
    }
    ts += __shfl_xor(ts, 16, 64);
    ts += __shfl_xor(ts, 32, 64);
    rl += ts;

    // ---- PV: O^T += V^T * P^T; V tile is s-permuted so one b128 per frag ----
    __builtin_amdgcn_s_setprio(1);
#pragma unroll
    for (int c = 0; c < 2; c++) {
      u32x4 bu = {pk[2 * c][0], pk[2 * c][1], pk[2 * c + 1][0], pk[2 * c + 1][1]};
      s16x8 bfrag = __builtin_bit_cast(s16x8, bu);
#pragma unroll
      for (int nf = 0; nf < 3; nf++) {
        int row = nf * 16 + lr;
        s16x8 afrag = *(const s16x8*)(
            vtp + ((row * 128 + c * 64 + lg * 16) ^ ((row & 7) << 4)));
        O[nf] = mfma_bf16(afrag, bfrag, O[nf]);
      }
    }
    __builtin_amdgcn_s_setprio(0);

    // write next tile into the other buffer; single barrier per iter
    if (t + 1 < 64) {
      *(s16x8*)(kt[p ^ 1] + kofs) = kreg;
      if (hasv) *(s16x8*)(vts[p ^ 1] + kofs) = vreg;
      __syncthreads();
    }
  }

  // ---- epilogue: O^T/rl -> AO[b][s][h*40+d] ----
  float inv = 1.f / rl;
#pragma unroll
  for (int nf = 0; nf < 3; nf++) {
#pragma unroll
    for (int r = 0; r < 4; r++) {
      int d = nf * 16 + lg * 4 + r;
      if (d < 40) {
        AO[((size_t)(b * 4096 + qrow)) * 320 + h * 40 + d] = f2bf(O[nf][r] * inv);
      }
    }
  }
}

// ---------------------------------------------------------------------------
extern "C" void kernel_launch(void* const* d_in, const int* in_sizes, int n_in,
                              void* d_out, int out_size, void* d_ws,
                              size_t ws_size, hipStream_t stream) {
  const float* x    = (const float*)d_in[0];
  const float* cond = (const float*)d_in[1];
  const float* Wq   = (const float*)d_in[2];
  const float* Wk   = (const float*)d_in[3];
  const float* Wv   = (const float*)d_in[4];
  const float* Wo   = (const float*)d_in[5];
  const float* bo   = (const float*)d_in[6];

  char* ws = (char*)d_ws;
  unsigned short* xb    = (unsigned short*)(ws + 0);          // 8192*320*2   = 5,242,880
  unsigned short* condb = (unsigned short*)(ws + 5242880);    // 8192*768*2   = 12,582,912
  unsigned short* WtQ   = (unsigned short*)(ws + 17825792);   // 320*320*2    = 204,800
  unsigned short* WtK   = (unsigned short*)(ws + 18030592);   // 768*320*2    = 491,520
  unsigned short* WtV   = (unsigned short*)(ws + 18522112);   // 768*320*2    = 491,520
  unsigned short* WtO   = (unsigned short*)(ws + 19013632);   // 320*320*2    = 204,800
  unsigned short* AO    = (unsigned short*)(ws + 19218432);   // 8192*320*2   = 5,242,880
  unsigned short* Qh    = (unsigned short*)(ws + 24461312);   // 16*4096*64*2 = 8,388,608
  unsigned short* Kh    = (unsigned short*)(ws + 32849920);   // 16*4096*64*2 = 8,388,608
  unsigned short* Vt    = (unsigned short*)(ws + 41238528);   // 16*48*4096*2 = 6,291,456
  // total = 47,529,984 bytes

  // zero padded Q/K/V buffers (d>=40 pads must be 0 for MFMA correctness)
  hipMemsetAsync(Qh, 0, 23068672, stream);

  convert_all<<<dim3(8704), 256, 0, stream>>>(x, cond, xb, condb);
  transpose_all<<<dim3(2720), 256, 0, stream>>>(Wq, Wk, Wv, Wo, WtQ, WtK, WtV, WtO);

  const float qscale = 1.44269504088896f / sqrtf(40.0f);  // log2(e)/sqrt(Dh)

  qkv_proj<<<dim3(128, 5, 3), 256, 0, stream>>>(xb, condb, WtQ, WtK, WtV, Qh, Kh, Vt,
                                                qscale);
  attn_kernel<<<dim3(32, 16), 512, 0, stream>>>(Qh, Kh, Vt, AO);
  o_proj<<<dim3(128, 5), 256, 0, stream>>>(AO, WtO, (float*)d_out, bo);
}